// Round 14
// baseline (106.447 us; speedup 1.0000x reference)
//
#include <hip/hip_runtime.h>
#include <cstdint>
#include <cstddef>

// HardDetectionModule: per-element detect = is_depth_wise_max & is_local_max & is_not_edge
// batch: (B=2, C=512, H=192, W=256) float32, row-major.
// Output: same shape, int32 0/1 (reference returns bool -> harness reads int32).
//
// R14: single-store recompute structure (deterministic by construction).
// History: interleaved zero-store+overwrite with NT = 60us but raced once
// (R11: NT zero on bypass path vs normal '1' on L2 path, unordered at DRAM);
// with plain stores = 91us (R13: write-allocate thrashes input in L2/L3);
// phase-separated single-store = 72us (R12: read & write streams serialized).
// R14: pass A = pure read (column maxes, no masks); pass B = re-stream input
// (L3-hit: 201MB input < 256MB L3, NT writes don't evict) recomputing the
// final 0/1 inline and issuing ONE NT store per element. Reads(L3) overlap
// writes(DRAM) in pass B; every address written exactly once.

namespace {

constexpr int Bn = 2;
constexpr int Cn = 512;
constexpr int Hn = 192;
constexpr int Wn = 256;
constexpr int CH  = Hn * Wn;         // channel stride in elements (49152)
constexpr int SEG = 8;               // wave-segments per column
constexpr int CPS = Cn / SEG;        // 64 channels per segment

// Local-max + Hessian edge test for candidate at flat index p (value v).
// f32 ops match numpy rounding; __fmul_rn blocks fma contraction.
__device__ __forceinline__ bool eval_candidate(
    const float* __restrict__ in, size_t p, float v,
    bool has_u, bool has_d, bool has_l, bool has_r) {
    const float nu  = has_u ? in[p - Wn] : 0.0f;
    const float nd  = has_d ? in[p + Wn] : 0.0f;
    const float nl  = has_l ? in[p - 1]  : 0.0f;
    const float nr  = has_r ? in[p + 1]  : 0.0f;
    const float nul = (has_u && has_l) ? in[p - Wn - 1] : 0.0f;
    const float nur = (has_u && has_r) ? in[p - Wn + 1] : 0.0f;
    const float ndl = (has_d && has_l) ? in[p + Wn - 1] : 0.0f;
    const float ndr = (has_d && has_r) ? in[p + Wn + 1] : 0.0f;

    const bool lm =
        (!has_u || v >= nu) && (!has_d || v >= nd) &&
        (!has_l || v >= nl) && (!has_r || v >= nr) &&
        (!(has_u && has_l) || v >= nul) &&
        (!(has_u && has_r) || v >= nur) &&
        (!(has_d && has_l) || v >= ndl) &&
        (!(has_d && has_r) || v >= ndr);
    if (!lm) return false;

    const float dii = (nu + nd) - 2.0f * v;
    const float djj = (nl + nr) - 2.0f * v;
    const float dij = 0.25f * (((nul - nur) - ndl) + ndr);
    const float det = __fmul_rn(dii, djj) - __fmul_rn(dij, dij);
    const float tr  = dii + djj;
    const float ratio = __fmul_rn(tr, tr) / det;   // inf/nan ok if det<=0
    return (det > 0.0f) && (ratio <= 7.2f);        // 36/5
}

__global__ __launch_bounds__(512)
void hard_detect_kernel(const float* __restrict__ in, int* __restrict__ out) {
    const int tid = threadIdx.x & 63;            // lane 0..63
    const int s   = threadIdx.x >> 6;            // segment (wave) 0..7
    const int j0  = blockIdx.x * 128 + tid * 2;  // even column of this lane's pair
    const int i   = blockIdx.y;                  // 0..191
    const int b   = blockIdx.z;                  // 0..1

    __shared__ float2 smax[SEG][64];             // segment max per (seg, lane)

    // element index of (b, c=0, i, j0)
    const size_t base = ((size_t)b * Cn * Hn + (size_t)i) * Wn + (size_t)j0;
    const size_t seg0 = base + (size_t)(s * CPS) * (size_t)CH;

    // ---- Pass A (pure read): segment column-maxes, 4 independent partial
    // chains per column so loads stream without a serial max dependency.
    float a0 = -__builtin_inff(), a1 = a0;
    float b0 = a0, b1 = a0, c0 = a0, c1 = a0, d0 = a0, d1 = a0;
    #pragma unroll
    for (int k = 0; k < CPS; k += 4) {
        const float2 v0 = *reinterpret_cast<const float2*>(&in[seg0 + (size_t)(k + 0) * CH]);
        const float2 v1 = *reinterpret_cast<const float2*>(&in[seg0 + (size_t)(k + 1) * CH]);
        const float2 v2 = *reinterpret_cast<const float2*>(&in[seg0 + (size_t)(k + 2) * CH]);
        const float2 v3 = *reinterpret_cast<const float2*>(&in[seg0 + (size_t)(k + 3) * CH]);
        a0 = fmaxf(a0, v0.x); a1 = fmaxf(a1, v0.y);
        b0 = fmaxf(b0, v1.x); b1 = fmaxf(b1, v1.y);
        c0 = fmaxf(c0, v2.x); c1 = fmaxf(c1, v2.y);
        d0 = fmaxf(d0, v3.x); d1 = fmaxf(d1, v3.y);
    }
    smax[s][tid] = make_float2(fmaxf(fmaxf(a0, b0), fmaxf(c0, d0)),
                               fmaxf(fmaxf(a1, b1), fmaxf(c1, d1)));

    __syncthreads();

    // Global column maxes = max over the 8 segment maxes.
    float Mg0 = smax[0][tid].x;
    float Mg1 = smax[0][tid].y;
    #pragma unroll
    for (int ss = 1; ss < SEG; ++ss) {
        Mg0 = fmaxf(Mg0, smax[ss][tid].x);
        Mg1 = fmaxf(Mg1, smax[ss][tid].y);
    }

    // Column edge flags (row flags depend on i only).
    const bool has_u  = (i > 0), has_d = (i < Hn - 1);
    const bool has_l0 = (j0 > 0);            // col j0 (has_r0 always true: j0<=254)
    const bool has_r1 = (j0 < Wn - 2);       // col j0+1 (has_l1 always true)

    // ---- Pass B: re-stream this segment (L3-hit), compute final 0/1 inline,
    // single NT 8B store per column pair. No address written twice.
    #pragma unroll 4
    for (int k = 0; k < CPS; ++k) {
        const size_t idx = seg0 + (size_t)k * (size_t)CH;
        const float2 v = *reinterpret_cast<const float2*>(&in[idx]);
        unsigned long long o = 0ULL;
        if (v.x == Mg0) {
            if (eval_candidate(in, idx,     v.x, has_u, has_d, has_l0, true))
                o |= 1ULL;
        }
        if (v.y == Mg1) {
            if (eval_candidate(in, idx + 1, v.y, has_u, has_d, true, has_r1))
                o |= (1ULL << 32);
        }
        __builtin_nontemporal_store(o,
            reinterpret_cast<unsigned long long*>(&out[idx]));
    }
}

} // namespace

extern "C" void kernel_launch(void* const* d_in, const int* in_sizes, int n_in,
                              void* d_out, int out_size, void* d_ws, size_t ws_size,
                              hipStream_t stream) {
    const float* in = (const float*)d_in[0];
    int* out = (int*)d_out;
    (void)in_sizes; (void)n_in; (void)out_size; (void)d_ws; (void)ws_size;

    dim3 grid(Wn / 128, Hn, Bn);   // 2 x 192 x 2 = 768 blocks x 8 waves (3/CU)
    dim3 block(512);
    hipLaunchKernelGGL(hard_detect_kernel, grid, block, 0, stream, in, out);
}